// Round 1
// baseline (544.336 us; speedup 1.0000x reference)
//
#include <hip/hip_runtime.h>
#include <math.h>

#define NB   1024   // batch
#define NG   2000   // gene groups
#define NGS  25     // group size
#define NH1  1024
#define NH2  512
#define NC   10
#define EPSV 1e-5f

// ---------------------------------------------------------------------------
// Stage 1: g[b,gi] = relu(dot(x[b, gi*25 : gi*25+25], gene_w[gi,:]) + gene_b[gi])
// One thread per output, g fastest -> coalesced store; x reads are 100B/lane
// strided but fully L1-resident within a wave's 6.4KB window.
// ---------------------------------------------------------------------------
__global__ __launch_bounds__(256) void gene_kernel(
    const float* __restrict__ x, const float* __restrict__ gw,
    const float* __restrict__ gb, float* __restrict__ g_out) {
  int idx = blockIdx.x * blockDim.x + threadIdx.x;   // b*NG + gi
  int b  = idx / NG;
  int gi = idx - b * NG;
  const float* xp = x + (size_t)b * (NG * NGS) + gi * NGS;
  const float* wp = gw + gi * NGS;
  float acc = 0.f;
#pragma unroll
  for (int k = 0; k < NGS; ++k) acc = fmaf(xp[k], wp[k], acc);
  acc += gb[gi];
  g_out[idx] = fmaxf(acc, 0.f);
}

// ---------------------------------------------------------------------------
// fp32 SGEMM: C[M,N] = A[M,K] * B[K,N] + bias[N]
// 64x64 block tile, 256 threads, 4x4 microtile, K-tile 16. All dims here are
// multiples of the tile sizes (K in {2000,1024} divisible by 16).
// ---------------------------------------------------------------------------
__global__ __launch_bounds__(256) void gemm_bias(
    const float* __restrict__ A, const float* __restrict__ Bm,
    const float* __restrict__ bias, float* __restrict__ C,
    int M, int N, int K) {
  __shared__ float As[16][64];   // As[k][m]
  __shared__ float Bs[16][64];   // Bs[k][n]
  int tid = threadIdx.x;
  int tx = tid & 15, ty = tid >> 4;
  int m0 = blockIdx.y * 64, n0 = blockIdx.x * 64;

  float acc[4][4] = {};

  int am = tid >> 2;          // 0..63  (row within A tile)
  int ak = (tid & 3) << 2;    // 0,4,8,12 (k within A tile)
  int bk = tid >> 4;          // 0..15  (k within B tile)
  int bn = (tid & 15) << 2;   // 0..60  (col within B tile)

  for (int k0 = 0; k0 < K; k0 += 16) {
    float4 av = *(const float4*)&A[(size_t)(m0 + am) * K + k0 + ak];
    float4 bv = *(const float4*)&Bm[(size_t)(k0 + bk) * N + n0 + bn];
    As[ak + 0][am] = av.x;
    As[ak + 1][am] = av.y;
    As[ak + 2][am] = av.z;
    As[ak + 3][am] = av.w;
    *(float4*)&Bs[bk][bn] = bv;
    __syncthreads();
#pragma unroll
    for (int kk = 0; kk < 16; ++kk) {
      float4 a = *(const float4*)&As[kk][ty << 2];
      float4 b = *(const float4*)&Bs[kk][tx << 2];
      float ar[4] = {a.x, a.y, a.z, a.w};
      float br[4] = {b.x, b.y, b.z, b.w};
#pragma unroll
      for (int i = 0; i < 4; ++i)
#pragma unroll
        for (int j = 0; j < 4; ++j)
          acc[i][j] = fmaf(ar[i], br[j], acc[i][j]);
    }
    __syncthreads();
  }

#pragma unroll
  for (int i = 0; i < 4; ++i) {
    int m = m0 + (ty << 2) + i;
#pragma unroll
    for (int j = 0; j < 4; ++j) {
      int n = n0 + (tx << 2) + j;
      C[(size_t)m * N + n] = acc[i][j] + bias[n];
    }
  }
}

// ---------------------------------------------------------------------------
// BatchNorm stats: per-column sum and sum-of-squares over 1024 rows.
// grid = (N/256, 16); each block covers 256 cols x 64 rows, atomics finalize.
// ---------------------------------------------------------------------------
__global__ __launch_bounds__(256) void bn_stats(
    const float* __restrict__ t, float* __restrict__ sum,
    float* __restrict__ sq, int N) {
  int c  = blockIdx.x * blockDim.x + threadIdx.x;
  int r0 = blockIdx.y * 64;
  float s = 0.f, ss = 0.f;
  for (int r = r0; r < r0 + 64; ++r) {
    float v = t[(size_t)r * N + c];
    s += v;
    ss = fmaf(v, v, ss);
  }
  atomicAdd(&sum[c], s);
  atomicAdd(&sq[c], ss);
}

// ---------------------------------------------------------------------------
// BatchNorm apply + ReLU, in place. N is a power of two (1024 or 512).
// ---------------------------------------------------------------------------
__global__ __launch_bounds__(256) void bn_apply(
    float* __restrict__ t, const float* __restrict__ sum,
    const float* __restrict__ sq, const float* __restrict__ gamma,
    const float* __restrict__ beta, int nmask) {
  int idx = blockIdx.x * blockDim.x + threadIdx.x;
  int c = idx & nmask;
  float mu  = sum[c] * (1.f / NB);
  float var = sq[c] * (1.f / NB) - mu * mu;
  float v = (t[idx] - mu) * rsqrtf(var + EPSV);
  t[idx] = fmaxf(fmaf(gamma[c], v, beta[c]), 0.f);
}

// ---------------------------------------------------------------------------
// Final heads + softmax: one block (256 threads = 4 waves) per batch row.
// logits[c] = h2[b,:]@Wout[:,c] + g[b,:]@Wres[:,c] + bout[c] + bres[c]
// ---------------------------------------------------------------------------
__global__ __launch_bounds__(256) void final_kernel(
    const float* __restrict__ h2, const float* __restrict__ g,
    const float* __restrict__ Wout, const float* __restrict__ bout,
    const float* __restrict__ Wres, const float* __restrict__ bres,
    float* __restrict__ out) {
  int b = blockIdx.x;
  float acc[NC] = {};

  for (int j = threadIdx.x; j < NH2; j += 256) {
    float v = h2[(size_t)b * NH2 + j];
#pragma unroll
    for (int c = 0; c < NC; ++c) acc[c] = fmaf(v, Wout[j * NC + c], acc[c]);
  }
  for (int j = threadIdx.x; j < NG; j += 256) {
    float v = g[(size_t)b * NG + j];
#pragma unroll
    for (int c = 0; c < NC; ++c) acc[c] = fmaf(v, Wres[j * NC + c], acc[c]);
  }

  __shared__ float red[4][NC];
  __shared__ float logits[NC];
  int lane = threadIdx.x & 63;
  int wave = threadIdx.x >> 6;
#pragma unroll
  for (int c = 0; c < NC; ++c) {
    float v = acc[c];
    for (int off = 32; off > 0; off >>= 1) v += __shfl_down(v, off, 64);
    if (lane == 0) red[wave][c] = v;
  }
  __syncthreads();
  if (threadIdx.x < NC) {
    int c = threadIdx.x;
    logits[c] = red[0][c] + red[1][c] + red[2][c] + red[3][c] + bout[c] + bres[c];
  }
  __syncthreads();
  if (threadIdx.x == 0) {
    float mx = logits[0];
#pragma unroll
    for (int c = 1; c < NC; ++c) mx = fmaxf(mx, logits[c]);
    float e[NC];
    float s = 0.f;
#pragma unroll
    for (int c = 0; c < NC; ++c) {
      e[c] = expf(logits[c] - mx);
      s += e[c];
    }
    float inv = 1.f / s;
#pragma unroll
    for (int c = 0; c < NC; ++c) out[(size_t)b * NC + c] = e[c] * inv;
  }
}

// ---------------------------------------------------------------------------
extern "C" void kernel_launch(void* const* d_in, const int* in_sizes, int n_in,
                              void* d_out, int out_size, void* d_ws, size_t ws_size,
                              hipStream_t stream) {
  const float* x      = (const float*)d_in[0];
  const float* gw     = (const float*)d_in[1];
  const float* gb     = (const float*)d_in[2];
  const float* W1     = (const float*)d_in[3];
  const float* b1     = (const float*)d_in[4];
  const float* gamma1 = (const float*)d_in[5];
  const float* beta1  = (const float*)d_in[6];
  const float* W2     = (const float*)d_in[7];
  const float* b2     = (const float*)d_in[8];
  const float* gamma2 = (const float*)d_in[9];
  const float* beta2  = (const float*)d_in[10];
  const float* Wout   = (const float*)d_in[11];
  const float* bout   = (const float*)d_in[12];
  const float* Wres   = (const float*)d_in[13];
  const float* bres   = (const float*)d_in[14];
  float* out = (float*)d_out;

  float* ws = (float*)d_ws;
  float* g     = ws;                 // 1024*2000 = 2,048,000
  float* t1    = g + 2048000;        // 1024*1024 = 1,048,576
  float* t2    = t1 + 1048576;       // 1024*512  =   524,288
  float* stats = t2 + 524288;        // 3072 floats
  float* sum1 = stats;
  float* sq1  = stats + 1024;
  float* sum2 = stats + 2048;
  float* sq2  = stats + 2560;

  // zero the BN stat accumulators (ws is poisoned to 0xAA before every call)
  hipMemsetAsync(stats, 0, 3072 * sizeof(float), stream);

  // Stage 1: gene layer
  gene_kernel<<<(NB * NG) / 256, 256, 0, stream>>>(x, gw, gb, g);

  // Stage 2: t1 = g @ W1 + b1
  gemm_bias<<<dim3(NH1 / 64, NB / 64), 256, 0, stream>>>(g, W1, b1, t1, NB, NH1, NG);

  // Stage 3: BN1 + ReLU (in place on t1)
  bn_stats<<<dim3(NH1 / 256, 16), 256, 0, stream>>>(t1, sum1, sq1, NH1);
  bn_apply<<<(NB * NH1) / 256, 256, 0, stream>>>(t1, sum1, sq1, gamma1, beta1, NH1 - 1);

  // Stage 4: t2 = h1 @ W2 + b2
  gemm_bias<<<dim3(NH2 / 64, NB / 64), 256, 0, stream>>>(t1, W2, b2, t2, NB, NH2, NH1);

  // Stage 5: BN2 + ReLU (in place on t2)
  bn_stats<<<dim3(NH2 / 256, 16), 256, 0, stream>>>(t2, sum2, sq2, NH2);
  bn_apply<<<(NB * NH2) / 256, 256, 0, stream>>>(t2, sum2, sq2, gamma2, beta2, NH2 - 1);

  // Stage 6: heads + softmax
  final_kernel<<<NB, 256, 0, stream>>>(t2, g, Wout, bout, Wres, bres, out);
}

// Round 2
// 385.977 us; speedup vs baseline: 1.4103x; 1.4103x over previous
//
#include <hip/hip_runtime.h>
#include <math.h>

#define NB   1024
#define NG   2000
#define NGS  25
#define KP   2048   // K padded to multiple of 64 for MFMA GEMM1
#define NH1  1024
#define NH2  512
#define NC   10
#define EPSV 1e-5f
#define GPB  200    // gene groups per block

typedef __attribute__((ext_vector_type(8))) __bf16 bf16x8;
typedef __attribute__((ext_vector_type(4))) float f32x4;
typedef __attribute__((ext_vector_type(8))) unsigned short u16x8;
typedef __attribute__((ext_vector_type(4))) unsigned short u16x4;

__device__ __forceinline__ unsigned short f2bf(float f) {
  union { float f; unsigned u; } v; v.f = f;
  return (unsigned short)((v.u + 0x7fffu + ((v.u >> 16) & 1u)) >> 16);
}
__device__ __forceinline__ float bf2f(unsigned short b) {
  union { unsigned u; float f; } v; v.u = ((unsigned)b) << 16;
  return v.f;
}

// ---------------------------------------------------------------------------
// Gene layer: coalesced float4 x-read into LDS, per-thread 25-elem dot from
// LDS (stride 25 across lanes -> 2 lanes/bank, free), emit bf16 g padded to
// KP cols (zeros in 2000..2047).  grid (NB, NG/GPB)
// ---------------------------------------------------------------------------
__global__ __launch_bounds__(256) void gene_kernel(
    const float* __restrict__ x, const float* __restrict__ gw,
    const float* __restrict__ gb, unsigned short* __restrict__ g_bf) {
  __shared__ float xs[GPB * NGS];   // 5000 floats = 20 KB
  int b = blockIdx.x;
  int blk = blockIdx.y;
  const float4* src = (const float4*)(x + (size_t)b * (NG * NGS) + blk * (GPB * NGS));
  float4* dst = (float4*)xs;
  for (int i = threadIdx.x; i < (GPB * NGS) / 4; i += 256) dst[i] = src[i];
  __syncthreads();
  int j = threadIdx.x;
  if (j < GPB) {
    int gi = blk * GPB + j;
    const float* wp = gw + gi * NGS;
    const float* xp = xs + j * NGS;
    float acc = 0.f;
#pragma unroll
    for (int k = 0; k < NGS; ++k) acc = fmaf(xp[k], wp[k], acc);
    acc += gb[gi];
    g_bf[(size_t)b * KP + gi] = f2bf(fmaxf(acc, 0.f));
  } else if (blk == (NG / GPB - 1) && j < GPB + (KP - NG)) {
    g_bf[(size_t)b * KP + NG + (j - GPB)] = 0;   // zero-pad k 2000..2047
  }
}

// ---------------------------------------------------------------------------
// Convert + transpose: src [K][N] fp32 -> dst [N][Kpad] bf16, zero for k>=K.
// 64x64 LDS tile (pad 72 to break conflicts). grid (Kpad/64, N/64)
// ---------------------------------------------------------------------------
__global__ __launch_bounds__(256) void convT_kernel(
    const float* __restrict__ src, unsigned short* __restrict__ dst,
    int K, int N, int Kpad) {
  __shared__ unsigned short ts[64][72];
  int k0 = blockIdx.x * 64, n0 = blockIdx.y * 64;
  int t = threadIdx.x;
  int c4 = (t & 15) * 4;
  int r  = t >> 4;
  for (int rr = r; rr < 64; rr += 16) {
    int k = k0 + rr;
    float4 v = make_float4(0.f, 0.f, 0.f, 0.f);
    if (k < K) v = *(const float4*)&src[(size_t)k * N + n0 + c4];
    ts[rr][c4 + 0] = f2bf(v.x); ts[rr][c4 + 1] = f2bf(v.y);
    ts[rr][c4 + 2] = f2bf(v.z); ts[rr][c4 + 3] = f2bf(v.w);
  }
  __syncthreads();
  int rr8 = (t & 7) * 8;
  int cc  = t >> 3;
  for (int c = cc; c < 64; c += 32) {
    u16x8 val;
#pragma unroll
    for (int i = 0; i < 8; ++i) val[i] = ts[rr8 + i][c];
    *(u16x8*)&dst[(size_t)(n0 + c) * Kpad + k0 + rr8] = val;
  }
}

// ---------------------------------------------------------------------------
// bf16 MFMA GEMM: C[M][N] = A[M][Kp] * Bt[N][Kp]^T  (fp32 accumulate/output).
// 64x64 block tile, BK=64, 4 waves each 32x32 (2x2 frags of 16x16x32).
// Padded LDS rows (72) -> 2-way bank aliasing only. Global prefetch in VGPRs.
// No bias: b1/b2 are cancelled by the following BatchNorm's mean subtraction.
// ---------------------------------------------------------------------------
__global__ __launch_bounds__(256) void gemm_bf16(
    const unsigned short* __restrict__ A,    // [M][Kp]
    const unsigned short* __restrict__ Bt,   // [N][Kp]
    float* __restrict__ C, int M, int N, int Kp) {
  __shared__ unsigned short As[64][72];
  __shared__ unsigned short Bs[64][72];
  int t = threadIdx.x;
  int m0 = blockIdx.y * 64, n0 = blockIdx.x * 64;
  int wave = t >> 6, lane = t & 63;
  int wm = (wave >> 1) * 32, wn = (wave & 1) * 32;
  int fm = lane & 15;          // fragment row (A) / row (B^T)
  int fk = (lane >> 4) * 8;    // fragment k-chunk

  int srow = t >> 3;           // staging row 0..31 (and +32)
  int skc  = (t & 7) * 8;      // staging k offset

  f32x4 acc[2][2];
#pragma unroll
  for (int i = 0; i < 2; ++i)
#pragma unroll
    for (int j = 0; j < 2; ++j) acc[i][j] = (f32x4){0.f, 0.f, 0.f, 0.f};

  const unsigned short* Ap = A + (size_t)(m0 + srow) * Kp + skc;
  const unsigned short* Bp = Bt + (size_t)(n0 + srow) * Kp + skc;
  size_t rstep = 32 * (size_t)Kp;

  u16x8 pa0 = *(const u16x8*)(Ap);
  u16x8 pa1 = *(const u16x8*)(Ap + rstep);
  u16x8 pb0 = *(const u16x8*)(Bp);
  u16x8 pb1 = *(const u16x8*)(Bp + rstep);

  for (int k0 = 0; k0 < Kp; k0 += 64) {
    *(u16x8*)&As[srow][skc]      = pa0;
    *(u16x8*)&As[srow + 32][skc] = pa1;
    *(u16x8*)&Bs[srow][skc]      = pb0;
    *(u16x8*)&Bs[srow + 32][skc] = pb1;
    __syncthreads();
    if (k0 + 64 < Kp) {            // prefetch next K-tile while computing
      pa0 = *(const u16x8*)(Ap + k0 + 64);
      pa1 = *(const u16x8*)(Ap + k0 + 64 + rstep);
      pb0 = *(const u16x8*)(Bp + k0 + 64);
      pb1 = *(const u16x8*)(Bp + k0 + 64 + rstep);
    }
#pragma unroll
    for (int s = 0; s < 2; ++s) {
      bf16x8 af[2], bfr[2];
      af[0]  = *(const bf16x8*)&As[wm + fm][s * 32 + fk];
      af[1]  = *(const bf16x8*)&As[wm + 16 + fm][s * 32 + fk];
      bfr[0] = *(const bf16x8*)&Bs[wn + fm][s * 32 + fk];
      bfr[1] = *(const bf16x8*)&Bs[wn + 16 + fm][s * 32 + fk];
#pragma unroll
      for (int i = 0; i < 2; ++i)
#pragma unroll
        for (int j = 0; j < 2; ++j)
          acc[i][j] = __builtin_amdgcn_mfma_f32_16x16x32_bf16(
              af[i], bfr[j], acc[i][j], 0, 0, 0);
    }
    __syncthreads();
  }

  int crow = (lane >> 4) * 4;   // C/D: row=(lane>>4)*4+reg, col=lane&15
  int ccol = lane & 15;
#pragma unroll
  for (int i = 0; i < 2; ++i)
#pragma unroll
    for (int j = 0; j < 2; ++j)
#pragma unroll
      for (int r = 0; r < 4; ++r) {
        int m = m0 + wm + i * 16 + crow + r;
        int n = n0 + wn + j * 16 + ccol;
        C[(size_t)m * N + n] = acc[i][j][r];
      }
}

// ---------------------------------------------------------------------------
// BN stats: per-column sum / sum-of-squares, atomics finalize.
// grid (N/256, 16); 64 rows per block.
// ---------------------------------------------------------------------------
__global__ __launch_bounds__(256) void bn_stats(
    const float* __restrict__ t, float* __restrict__ sum,
    float* __restrict__ sq, int N) {
  int c  = blockIdx.x * blockDim.x + threadIdx.x;
  int r0 = blockIdx.y * 64;
  float s = 0.f, ss = 0.f;
  for (int r = r0; r < r0 + 64; ++r) {
    float v = t[(size_t)r * N + c];
    s += v;
    ss = fmaf(v, v, ss);
  }
  atomicAdd(&sum[c], s);
  atomicAdd(&sq[c], ss);
}

// BN apply + ReLU -> bf16 out (feeds next MFMA GEMM). x4 vectorized.
__global__ __launch_bounds__(256) void bn_apply_bf16(
    const float* __restrict__ t, unsigned short* __restrict__ o,
    const float* __restrict__ sum, const float* __restrict__ sq,
    const float* __restrict__ gamma, const float* __restrict__ beta,
    int nmask) {
  int idx = (blockIdx.x * 256 + threadIdx.x) * 4;
  float4 v = *(const float4*)&t[idx];
  float vv[4] = {v.x, v.y, v.z, v.w};
  u16x4 ov;
#pragma unroll
  for (int i = 0; i < 4; ++i) {
    int c = (idx + i) & nmask;
    float mu  = sum[c] * (1.f / NB);
    float var = sq[c] * (1.f / NB) - mu * mu;
    float h = (vv[i] - mu) * rsqrtf(var + EPSV);
    ov[i] = f2bf(fmaxf(fmaf(gamma[c], h, beta[c]), 0.f));
  }
  *(u16x4*)&o[idx] = ov;
}

// BN apply + ReLU, fp32 in-place (feeds final head). x4 vectorized.
__global__ __launch_bounds__(256) void bn_apply_f32(
    float* __restrict__ t, const float* __restrict__ sum,
    const float* __restrict__ sq, const float* __restrict__ gamma,
    const float* __restrict__ beta, int nmask) {
  int idx = (blockIdx.x * 256 + threadIdx.x) * 4;
  float4 v = *(const float4*)&t[idx];
  float vv[4] = {v.x, v.y, v.z, v.w};
#pragma unroll
  for (int i = 0; i < 4; ++i) {
    int c = (idx + i) & nmask;
    float mu  = sum[c] * (1.f / NB);
    float var = sq[c] * (1.f / NB) - mu * mu;
    float h = (vv[i] - mu) * rsqrtf(var + EPSV);
    vv[i] = fmaxf(fmaf(gamma[c], h, beta[c]), 0.f);
  }
  *(float4*)&t[idx] = make_float4(vv[0], vv[1], vv[2], vv[3]);
}

// ---------------------------------------------------------------------------
// Final heads + softmax: block per row; float4-vectorized g/Wres/Wout reads.
// ---------------------------------------------------------------------------
__global__ __launch_bounds__(256) void final_kernel(
    const float* __restrict__ h2, const unsigned short* __restrict__ g_bf,
    const float* __restrict__ Wout, const float* __restrict__ bout,
    const float* __restrict__ Wres, const float* __restrict__ bres,
    float* __restrict__ out) {
  int b = blockIdx.x;
  int t = threadIdx.x;
  float acc[NC] = {};

  if (t < NH2 / 4) {   // main head: 128 units of 4 h2-elems
    float4 hv = *(const float4*)&h2[(size_t)b * NH2 + t * 4];
    float hr[4] = {hv.x, hv.y, hv.z, hv.w};
    const float4* wp = (const float4*)&Wout[t * 4 * NC];
    float w[40];
#pragma unroll
    for (int q = 0; q < 10; ++q) {
      float4 wv = wp[q];
      w[q * 4] = wv.x; w[q * 4 + 1] = wv.y; w[q * 4 + 2] = wv.z; w[q * 4 + 3] = wv.w;
    }
#pragma unroll
    for (int r = 0; r < 4; ++r)
#pragma unroll
      for (int c = 0; c < NC; ++c) acc[c] = fmaf(hr[r], w[r * NC + c], acc[c]);
  }

  for (int u = t; u < NG / 4; u += 256) {   // residual head: 500 units
    u16x4 gv = *(const u16x4*)&g_bf[(size_t)b * KP + u * 4];
    float gr[4] = {bf2f(gv[0]), bf2f(gv[1]), bf2f(gv[2]), bf2f(gv[3])};
    const float4* wp = (const float4*)&Wres[u * 4 * NC];
    float w[40];
#pragma unroll
    for (int q = 0; q < 10; ++q) {
      float4 wv = wp[q];
      w[q * 4] = wv.x; w[q * 4 + 1] = wv.y; w[q * 4 + 2] = wv.z; w[q * 4 + 3] = wv.w;
    }
#pragma unroll
    for (int r = 0; r < 4; ++r)
#pragma unroll
      for (int c = 0; c < NC; ++c) acc[c] = fmaf(gr[r], w[r * NC + c], acc[c]);
  }

  __shared__ float red[4][NC];
  __shared__ float logits[NC];
  int lane = t & 63, wave = t >> 6;
#pragma unroll
  for (int c = 0; c < NC; ++c) {
    float v = acc[c];
    for (int off = 32; off > 0; off >>= 1) v += __shfl_down(v, off, 64);
    if (lane == 0) red[wave][c] = v;
  }
  __syncthreads();
  if (t < NC)
    logits[t] = red[0][t] + red[1][t] + red[2][t] + red[3][t] + bout[t] + bres[t];
  __syncthreads();
  if (t == 0) {
    float mx = logits[0];
#pragma unroll
    for (int c = 1; c < NC; ++c) mx = fmaxf(mx, logits[c]);
    float e[NC], s = 0.f;
#pragma unroll
    for (int c = 0; c < NC; ++c) { e[c] = expf(logits[c] - mx); s += e[c]; }
    float inv = 1.f / s;
#pragma unroll
    for (int c = 0; c < NC; ++c) out[(size_t)b * NC + c] = e[c] * inv;
  }
}

// ---------------------------------------------------------------------------
extern "C" void kernel_launch(void* const* d_in, const int* in_sizes, int n_in,
                              void* d_out, int out_size, void* d_ws, size_t ws_size,
                              hipStream_t stream) {
  const float* x      = (const float*)d_in[0];
  const float* gw     = (const float*)d_in[1];
  const float* gb     = (const float*)d_in[2];
  const float* W1     = (const float*)d_in[3];
  const float* gamma1 = (const float*)d_in[5];
  const float* beta1  = (const float*)d_in[6];
  const float* W2     = (const float*)d_in[7];
  const float* gamma2 = (const float*)d_in[9];
  const float* beta2  = (const float*)d_in[10];
  const float* Wout   = (const float*)d_in[11];
  const float* bout   = (const float*)d_in[12];
  const float* Wres   = (const float*)d_in[13];
  const float* bres   = (const float*)d_in[14];
  float* out = (float*)d_out;

  // workspace layout (bytes): 17.8 MB total
  char* p = (char*)d_ws;
  unsigned short* g_bf  = (unsigned short*)p; p += (size_t)NB * KP * 2;        // 4 MB
  unsigned short* W1bT  = (unsigned short*)p; p += (size_t)NH1 * KP * 2;       // 4 MB
  unsigned short* W2bT  = (unsigned short*)p; p += (size_t)NH2 * NH1 * 2;      // 1 MB
  float* t1  = (float*)p; p += (size_t)NB * NH1 * 4;                           // 4 MB
  unsigned short* t1b = (unsigned short*)p; p += (size_t)NB * NH1 * 2;         // 2 MB
  float* t2  = (float*)p; p += (size_t)NB * NH2 * 4;                           // 2 MB
  float* stats = (float*)p;
  float* sum1 = stats, *sq1 = stats + 1024, *sum2 = stats + 2048, *sq2 = stats + 2560;

  hipMemsetAsync(stats, 0, 3072 * sizeof(float), stream);

  // weight convert+transpose (per call; weights are call-invariant inputs)
  convT_kernel<<<dim3(KP / 64, NH1 / 64), 256, 0, stream>>>(W1, W1bT, NG, NH1, KP);
  convT_kernel<<<dim3(NH1 / 64, NH2 / 64), 256, 0, stream>>>(W2, W2bT, NH1, NH2, NH1);

  // gene layer -> g_bf [NB][KP]
  gene_kernel<<<dim3(NB, NG / GPB), 256, 0, stream>>>(x, gw, gb, g_bf);

  // GEMM1: t1 = g @ W1   (bias cancelled by BN)
  gemm_bf16<<<dim3(NH1 / 64, NB / 64), 256, 0, stream>>>(g_bf, W1bT, t1, NB, NH1, KP);
  bn_stats<<<dim3(NH1 / 256, 16), 256, 0, stream>>>(t1, sum1, sq1, NH1);
  bn_apply_bf16<<<(NB * NH1 / 4) / 256, 256, 0, stream>>>(t1, t1b, sum1, sq1,
                                                          gamma1, beta1, NH1 - 1);

  // GEMM2: t2 = h1 @ W2
  gemm_bf16<<<dim3(NH2 / 64, NB / 64), 256, 0, stream>>>(t1b, W2bT, t2, NB, NH2, NH1);
  bn_stats<<<dim3(NH2 / 256, 16), 256, 0, stream>>>(t2, sum2, sq2, NH2);
  bn_apply_f32<<<(NB * NH2 / 4) / 256, 256, 0, stream>>>(t2, sum2, sq2,
                                                         gamma2, beta2, NH2 - 1);

  // heads + softmax
  final_kernel<<<NB, 256, 0, stream>>>(t2, g_bf, Wout, bout, Wres, bres, out);
}

// Round 3
// 372.467 us; speedup vs baseline: 1.4614x; 1.0363x over previous
//
#include <hip/hip_runtime.h>
#include <math.h>

#define NB   1024
#define NG   2000
#define NGS  25
#define KP   2048   // K padded to multiple of 64 for MFMA GEMM1
#define NH1  1024
#define NH2  512
#define NC   10
#define EPSV 1e-5f
#define GPB  200    // gene groups per block

typedef __attribute__((ext_vector_type(8))) __bf16 bf16x8;
typedef __attribute__((ext_vector_type(4))) float f32x4;
typedef __attribute__((ext_vector_type(8))) unsigned short u16x8;
typedef __attribute__((ext_vector_type(4))) unsigned short u16x4;

__device__ __forceinline__ unsigned short f2bf(float f) {
  union { float f; unsigned u; } v; v.f = f;
  return (unsigned short)((v.u + 0x7fffu + ((v.u >> 16) & 1u)) >> 16);
}
__device__ __forceinline__ float bf2f(unsigned short b) {
  union { unsigned u; float f; } v; v.u = ((unsigned)b) << 16;
  return v.f;
}

// ---------------------------------------------------------------------------
// Gene layer: coalesced float4 x-read into LDS, per-thread 25-elem dot,
// emit bf16 g padded to KP cols.  grid (NB, NG/GPB)
// ---------------------------------------------------------------------------
__global__ __launch_bounds__(256) void gene_kernel(
    const float* __restrict__ x, const float* __restrict__ gw,
    const float* __restrict__ gb, unsigned short* __restrict__ g_bf) {
  __shared__ float xs[GPB * NGS];   // 20 KB
  int b = blockIdx.x;
  int blk = blockIdx.y;
  const float4* src = (const float4*)(x + (size_t)b * (NG * NGS) + blk * (GPB * NGS));
  float4* dst = (float4*)xs;
  for (int i = threadIdx.x; i < (GPB * NGS) / 4; i += 256) dst[i] = src[i];
  __syncthreads();
  int j = threadIdx.x;
  if (j < GPB) {
    int gi = blk * GPB + j;
    const float* wp = gw + gi * NGS;
    const float* xp = xs + j * NGS;
    float acc = 0.f;
#pragma unroll
    for (int k = 0; k < NGS; ++k) acc = fmaf(xp[k], wp[k], acc);
    acc += gb[gi];
    g_bf[(size_t)b * KP + gi] = f2bf(fmaxf(acc, 0.f));
  } else if (blk == (NG / GPB - 1) && j < GPB + (KP - NG)) {
    g_bf[(size_t)b * KP + NG + (j - GPB)] = 0;   // zero-pad k 2000..2047
  }
}

// ---------------------------------------------------------------------------
// Convert + transpose both weight matrices in ONE dispatch (z selects).
// src [K][N] fp32 -> dst [N][Kpad] bf16, zeros for k>=K.
// ---------------------------------------------------------------------------
__global__ __launch_bounds__(256) void convT_dual(
    const float* __restrict__ W1, unsigned short* __restrict__ W1bT,
    const float* __restrict__ W2, unsigned short* __restrict__ W2bT) {
  const float* src; unsigned short* dst; int K, N, Kpad;
  if (blockIdx.z == 0) { src = W1; dst = W1bT; K = NG; N = NH1; Kpad = KP; }
  else {
    src = W2; dst = W2bT; K = NH1; N = NH2; Kpad = NH1;
    if (blockIdx.x >= NH1 / 64 || blockIdx.y >= NH2 / 64) return;
  }
  __shared__ unsigned short ts[64][72];
  int k0 = blockIdx.x * 64, n0 = blockIdx.y * 64;
  int t = threadIdx.x;
  int c4 = (t & 15) * 4;
  int r  = t >> 4;
  for (int rr = r; rr < 64; rr += 16) {
    int k = k0 + rr;
    float4 v = make_float4(0.f, 0.f, 0.f, 0.f);
    if (k < K) v = *(const float4*)&src[(size_t)k * N + n0 + c4];
    ts[rr][c4 + 0] = f2bf(v.x); ts[rr][c4 + 1] = f2bf(v.y);
    ts[rr][c4 + 2] = f2bf(v.z); ts[rr][c4 + 3] = f2bf(v.w);
  }
  __syncthreads();
  int rr8 = (t & 7) * 8;
  int cc  = t >> 3;
  for (int c = cc; c < 64; c += 32) {
    u16x8 val;
#pragma unroll
    for (int i = 0; i < 8; ++i) val[i] = ts[rr8 + i][c];
    *(u16x8*)&dst[(size_t)(n0 + c) * Kpad + k0 + rr8] = val;
  }
}

// ---------------------------------------------------------------------------
// GEMM1: C = A(bf16) * Bt(bf16)^T, fp32 out, fused per-column sum/sumsq
// (BatchNorm stats) via wave shuffle-reduce + one atomic per column per wave.
// ---------------------------------------------------------------------------
__global__ __launch_bounds__(256) void gemm1_kernel(
    const unsigned short* __restrict__ A,    // [M][Kp]
    const unsigned short* __restrict__ Bt,   // [N][Kp]
    float* __restrict__ C, float* __restrict__ sum, float* __restrict__ sq,
    int M, int N, int Kp) {
  __shared__ unsigned short As[64][72];
  __shared__ unsigned short Bs[64][72];
  int t = threadIdx.x;
  int m0 = blockIdx.y * 64, n0 = blockIdx.x * 64;
  int wave = t >> 6, lane = t & 63;
  int wm = (wave >> 1) * 32, wn = (wave & 1) * 32;
  int fm = lane & 15, fk = (lane >> 4) * 8;
  int srow = t >> 3, skc = (t & 7) * 8;

  f32x4 acc[2][2];
#pragma unroll
  for (int i = 0; i < 2; ++i)
#pragma unroll
    for (int j = 0; j < 2; ++j) acc[i][j] = (f32x4){0.f, 0.f, 0.f, 0.f};

  const unsigned short* Ap = A + (size_t)(m0 + srow) * Kp + skc;
  const unsigned short* Bp = Bt + (size_t)(n0 + srow) * Kp + skc;
  size_t rstep = 32 * (size_t)Kp;

  u16x8 pa0 = *(const u16x8*)(Ap);
  u16x8 pa1 = *(const u16x8*)(Ap + rstep);
  u16x8 pb0 = *(const u16x8*)(Bp);
  u16x8 pb1 = *(const u16x8*)(Bp + rstep);

  for (int k0 = 0; k0 < Kp; k0 += 64) {
    *(u16x8*)&As[srow][skc]      = pa0;
    *(u16x8*)&As[srow + 32][skc] = pa1;
    *(u16x8*)&Bs[srow][skc]      = pb0;
    *(u16x8*)&Bs[srow + 32][skc] = pb1;
    __syncthreads();
    if (k0 + 64 < Kp) {
      pa0 = *(const u16x8*)(Ap + k0 + 64);
      pa1 = *(const u16x8*)(Ap + k0 + 64 + rstep);
      pb0 = *(const u16x8*)(Bp + k0 + 64);
      pb1 = *(const u16x8*)(Bp + k0 + 64 + rstep);
    }
#pragma unroll
    for (int s = 0; s < 2; ++s) {
      bf16x8 af[2], bfr[2];
      af[0]  = *(const bf16x8*)&As[wm + fm][s * 32 + fk];
      af[1]  = *(const bf16x8*)&As[wm + 16 + fm][s * 32 + fk];
      bfr[0] = *(const bf16x8*)&Bs[wn + fm][s * 32 + fk];
      bfr[1] = *(const bf16x8*)&Bs[wn + 16 + fm][s * 32 + fk];
#pragma unroll
      for (int i = 0; i < 2; ++i)
#pragma unroll
        for (int j = 0; j < 2; ++j)
          acc[i][j] = __builtin_amdgcn_mfma_f32_16x16x32_bf16(
              af[i], bfr[j], acc[i][j], 0, 0, 0);
    }
    __syncthreads();
  }

  int crow = (lane >> 4) * 4, ccol = lane & 15;
#pragma unroll
  for (int j = 0; j < 2; ++j) {
    float s = 0.f, ss = 0.f;
#pragma unroll
    for (int i = 0; i < 2; ++i)
#pragma unroll
      for (int r = 0; r < 4; ++r) {
        float v = acc[i][j][r];
        int m = m0 + wm + i * 16 + crow + r;
        int n = n0 + wn + j * 16 + ccol;
        C[(size_t)m * N + n] = v;
        s += v;
        ss = fmaf(v, v, ss);
      }
    s  += __shfl_down(s, 32, 64);  s  += __shfl_down(s, 16, 64);
    ss += __shfl_down(ss, 32, 64); ss += __shfl_down(ss, 16, 64);
    if (lane < 16) {
      atomicAdd(&sum[n0 + wn + j * 16 + lane], s);
      atomicAdd(&sq[n0 + wn + j * 16 + lane], ss);
    }
  }
}

// ---------------------------------------------------------------------------
// GEMM2: A = t1 fp32 with BN1(scale/shift from raw sums)+ReLU applied during
// LDS staging (-> bf16); B = W2bT bf16. Fused BN2 stats epilogue.
// ---------------------------------------------------------------------------
__global__ __launch_bounds__(256) void gemm2_kernel(
    const float* __restrict__ A,             // [M][Kp] fp32 (t1, pre-BN)
    const unsigned short* __restrict__ Bt,   // [N][Kp] bf16
    float* __restrict__ C, const float* __restrict__ sum1,
    const float* __restrict__ sq1, const float* __restrict__ gam1,
    const float* __restrict__ bet1, float* __restrict__ sum2,
    float* __restrict__ sq2, int M, int N, int Kp) {
  __shared__ unsigned short As[64][72];
  __shared__ unsigned short Bs[64][72];
  int t = threadIdx.x;
  int m0 = blockIdx.y * 64, n0 = blockIdx.x * 64;
  int wave = t >> 6, lane = t & 63;
  int wm = (wave >> 1) * 32, wn = (wave & 1) * 32;
  int fm = lane & 15, fk = (lane >> 4) * 8;
  int srow = t >> 3, skc = (t & 7) * 8;

  f32x4 acc[2][2];
#pragma unroll
  for (int i = 0; i < 2; ++i)
#pragma unroll
    for (int j = 0; j < 2; ++j) acc[i][j] = (f32x4){0.f, 0.f, 0.f, 0.f};

  const float* Ap = A + (size_t)(m0 + srow) * Kp + skc;
  const unsigned short* Bp = Bt + (size_t)(n0 + srow) * Kp + skc;
  size_t rstepA = 32 * (size_t)Kp;
  size_t rstepB = 32 * (size_t)Kp;

  f32x4 pa[4];
  pa[0] = *(const f32x4*)(Ap);
  pa[1] = *(const f32x4*)(Ap + 4);
  pa[2] = *(const f32x4*)(Ap + rstepA);
  pa[3] = *(const f32x4*)(Ap + rstepA + 4);
  u16x8 pb0 = *(const u16x8*)(Bp);
  u16x8 pb1 = *(const u16x8*)(Bp + rstepB);

  for (int k0 = 0; k0 < Kp; k0 += 64) {
    // BN1 scale/shift for k = k0+skc+i (same 64 values for all rows -> L1 hot)
    float sc[8], sh[8];
#pragma unroll
    for (int i = 0; i < 8; ++i) {
      int k = k0 + skc + i;
      float mu  = sum1[k] * (1.f / NB);
      float var = sq1[k] * (1.f / NB) - mu * mu;
      float rs  = rsqrtf(var + EPSV);
      sc[i] = gam1[k] * rs;
      sh[i] = fmaf(-mu, sc[i], bet1[k]);
    }
    u16x8 a0, a1;
#pragma unroll
    for (int i = 0; i < 4; ++i) {
      a0[i]     = f2bf(fmaxf(fmaf(pa[0][i], sc[i],     sh[i]),     0.f));
      a0[i + 4] = f2bf(fmaxf(fmaf(pa[1][i], sc[i + 4], sh[i + 4]), 0.f));
      a1[i]     = f2bf(fmaxf(fmaf(pa[2][i], sc[i],     sh[i]),     0.f));
      a1[i + 4] = f2bf(fmaxf(fmaf(pa[3][i], sc[i + 4], sh[i + 4]), 0.f));
    }
    *(u16x8*)&As[srow][skc]      = a0;
    *(u16x8*)&As[srow + 32][skc] = a1;
    *(u16x8*)&Bs[srow][skc]      = pb0;
    *(u16x8*)&Bs[srow + 32][skc] = pb1;
    __syncthreads();
    if (k0 + 64 < Kp) {
      pa[0] = *(const f32x4*)(Ap + k0 + 64);
      pa[1] = *(const f32x4*)(Ap + k0 + 64 + 4);
      pa[2] = *(const f32x4*)(Ap + k0 + 64 + rstepA);
      pa[3] = *(const f32x4*)(Ap + k0 + 64 + rstepA + 4);
      pb0 = *(const u16x8*)(Bp + k0 + 64);
      pb1 = *(const u16x8*)(Bp + k0 + 64 + rstepB);
    }
#pragma unroll
    for (int s = 0; s < 2; ++s) {
      bf16x8 af[2], bfr[2];
      af[0]  = *(const bf16x8*)&As[wm + fm][s * 32 + fk];
      af[1]  = *(const bf16x8*)&As[wm + 16 + fm][s * 32 + fk];
      bfr[0] = *(const bf16x8*)&Bs[wn + fm][s * 32 + fk];
      bfr[1] = *(const bf16x8*)&Bs[wn + 16 + fm][s * 32 + fk];
#pragma unroll
      for (int i = 0; i < 2; ++i)
#pragma unroll
        for (int j = 0; j < 2; ++j)
          acc[i][j] = __builtin_amdgcn_mfma_f32_16x16x32_bf16(
              af[i], bfr[j], acc[i][j], 0, 0, 0);
    }
    __syncthreads();
  }

  int crow = (lane >> 4) * 4, ccol = lane & 15;
#pragma unroll
  for (int j = 0; j < 2; ++j) {
    float s = 0.f, ss = 0.f;
#pragma unroll
    for (int i = 0; i < 2; ++i)
#pragma unroll
      for (int r = 0; r < 4; ++r) {
        float v = acc[i][j][r];
        int m = m0 + wm + i * 16 + crow + r;
        int n = n0 + wn + j * 16 + ccol;
        C[(size_t)m * N + n] = v;
        s += v;
        ss = fmaf(v, v, ss);
      }
    s  += __shfl_down(s, 32, 64);  s  += __shfl_down(s, 16, 64);
    ss += __shfl_down(ss, 32, 64); ss += __shfl_down(ss, 16, 64);
    if (lane < 16) {
      atomicAdd(&sum2[n0 + wn + j * 16 + lane], s);
      atomicAdd(&sq2[n0 + wn + j * 16 + lane], ss);
    }
  }
}

// ---------------------------------------------------------------------------
// Final: BN2(inline)+ReLU on t2 row, both heads, softmax. Block per row.
// ---------------------------------------------------------------------------
__global__ __launch_bounds__(256) void final_kernel(
    const float* __restrict__ t2, const float* __restrict__ sum2,
    const float* __restrict__ sq2, const float* __restrict__ gam2,
    const float* __restrict__ bet2, const unsigned short* __restrict__ g_bf,
    const float* __restrict__ Wout, const float* __restrict__ bout,
    const float* __restrict__ Wres, const float* __restrict__ bres,
    float* __restrict__ out) {
  int b = blockIdx.x;
  int t = threadIdx.x;
  float acc[NC] = {};

  if (t < NH2 / 4) {   // main head: 128 units of 4 h2-elems, BN2 inline
    float4 tv = *(const float4*)&t2[(size_t)b * NH2 + t * 4];
    float raw[4] = {tv.x, tv.y, tv.z, tv.w};
    float hr[4];
#pragma unroll
    for (int i = 0; i < 4; ++i) {
      int c = t * 4 + i;
      float mu  = sum2[c] * (1.f / NB);
      float var = sq2[c] * (1.f / NB) - mu * mu;
      float rs  = rsqrtf(var + EPSV);
      float scv = gam2[c] * rs;
      hr[i] = fmaxf(fmaf(raw[i], scv, fmaf(-mu, scv, bet2[c])), 0.f);
    }
    const float4* wp = (const float4*)&Wout[t * 4 * NC];
    float w[40];
#pragma unroll
    for (int q = 0; q < 10; ++q) {
      float4 wv = wp[q];
      w[q * 4] = wv.x; w[q * 4 + 1] = wv.y; w[q * 4 + 2] = wv.z; w[q * 4 + 3] = wv.w;
    }
#pragma unroll
    for (int r = 0; r < 4; ++r)
#pragma unroll
      for (int c = 0; c < NC; ++c) acc[c] = fmaf(hr[r], w[r * NC + c], acc[c]);
  }

  for (int u = t; u < NG / 4; u += 256) {   // residual head
    u16x4 gv = *(const u16x4*)&g_bf[(size_t)b * KP + u * 4];
    float gr[4] = {bf2f(gv[0]), bf2f(gv[1]), bf2f(gv[2]), bf2f(gv[3])};
    const float4* wp = (const float4*)&Wres[u * 4 * NC];
    float w[40];
#pragma unroll
    for (int q = 0; q < 10; ++q) {
      float4 wv = wp[q];
      w[q * 4] = wv.x; w[q * 4 + 1] = wv.y; w[q * 4 + 2] = wv.z; w[q * 4 + 3] = wv.w;
    }
#pragma unroll
    for (int r = 0; r < 4; ++r)
#pragma unroll
      for (int c = 0; c < NC; ++c) acc[c] = fmaf(gr[r], w[r * NC + c], acc[c]);
  }

  __shared__ float red[4][NC];
  __shared__ float logits[NC];
  int lane = t & 63, wave = t >> 6;
#pragma unroll
  for (int c = 0; c < NC; ++c) {
    float v = acc[c];
    for (int off = 32; off > 0; off >>= 1) v += __shfl_down(v, off, 64);
    if (lane == 0) red[wave][c] = v;
  }
  __syncthreads();
  if (t < NC)
    logits[t] = red[0][t] + red[1][t] + red[2][t] + red[3][t] + bout[t] + bres[t];
  __syncthreads();
  if (t == 0) {
    float mx = logits[0];
#pragma unroll
    for (int c = 1; c < NC; ++c) mx = fmaxf(mx, logits[c]);
    float e[NC], s = 0.f;
#pragma unroll
    for (int c = 0; c < NC; ++c) { e[c] = expf(logits[c] - mx); s += e[c]; }
    float inv = 1.f / s;
#pragma unroll
    for (int c = 0; c < NC; ++c) out[(size_t)b * NC + c] = e[c] * inv;
  }
}

// ---------------------------------------------------------------------------
extern "C" void kernel_launch(void* const* d_in, const int* in_sizes, int n_in,
                              void* d_out, int out_size, void* d_ws, size_t ws_size,
                              hipStream_t stream) {
  const float* x      = (const float*)d_in[0];
  const float* gw     = (const float*)d_in[1];
  const float* gb     = (const float*)d_in[2];
  const float* W1     = (const float*)d_in[3];
  const float* gamma1 = (const float*)d_in[5];
  const float* beta1  = (const float*)d_in[6];
  const float* W2     = (const float*)d_in[7];
  const float* gamma2 = (const float*)d_in[9];
  const float* beta2  = (const float*)d_in[10];
  const float* Wout   = (const float*)d_in[11];
  const float* bout   = (const float*)d_in[12];
  const float* Wres   = (const float*)d_in[13];
  const float* bres   = (const float*)d_in[14];
  float* out = (float*)d_out;

  char* p = (char*)d_ws;
  unsigned short* g_bf = (unsigned short*)p; p += (size_t)NB * KP * 2;    // 4 MB
  unsigned short* W1bT = (unsigned short*)p; p += (size_t)NH1 * KP * 2;   // 4 MB
  unsigned short* W2bT = (unsigned short*)p; p += (size_t)NH2 * NH1 * 2;  // 1 MB
  float* t1 = (float*)p; p += (size_t)NB * NH1 * 4;                       // 4 MB
  float* t2 = (float*)p; p += (size_t)NB * NH2 * 4;                       // 2 MB
  float* stats = (float*)p;
  float* sum1 = stats, *sq1 = stats + 1024, *sum2 = stats + 2048, *sq2 = stats + 2560;

  hipMemsetAsync(stats, 0, 3072 * sizeof(float), stream);

  convT_dual<<<dim3(KP / 64, NH1 / 64, 2), 256, 0, stream>>>(W1, W1bT, W2, W2bT);

  gene_kernel<<<dim3(NB, NG / GPB), 256, 0, stream>>>(x, gw, gb, g_bf);

  gemm1_kernel<<<dim3(NH1 / 64, NB / 64), 256, 0, stream>>>(
      g_bf, W1bT, t1, sum1, sq1, NB, NH1, KP);

  gemm2_kernel<<<dim3(NH2 / 64, NB / 64), 256, 0, stream>>>(
      t1, W2bT, t2, sum1, sq1, gamma1, beta1, sum2, sq2, NB, NH2, NH1);

  final_kernel<<<NB, 256, 0, stream>>>(t2, sum2, sq2, gamma2, beta2, g_bf,
                                       Wout, bout, Wres, bres, out);
}

// Round 4
// 366.245 us; speedup vs baseline: 1.4863x; 1.0170x over previous
//
#include <hip/hip_runtime.h>
#include <math.h>

#define NB   1024
#define NG   2000
#define NGS  25
#define KP   2048   // K padded to multiple of 64 for MFMA GEMM1
#define NH1  1024
#define NH2  512
#define NC   10
#define EPSV 1e-5f
#define GPB  200    // gene groups per block

typedef __attribute__((ext_vector_type(8))) __bf16 bf16x8;
typedef __attribute__((ext_vector_type(4))) float f32x4;
typedef __attribute__((ext_vector_type(8))) unsigned short u16x8;
typedef __attribute__((ext_vector_type(4))) unsigned short u16x4;

__device__ __forceinline__ unsigned short f2bf(float f) {
  union { float f; unsigned u; } v; v.f = f;
  return (unsigned short)((v.u + 0x7fffu + ((v.u >> 16) & 1u)) >> 16);
}
__device__ __forceinline__ float bf2f(unsigned short b) {
  union { unsigned u; float f; } v; v.u = ((unsigned)b) << 16;
  return v.f;
}

// ---------------------------------------------------------------------------
// Prep + gene dispatch. grid (1024, 11):
//   y < 10 : gene layer block (batch row b = x, group-chunk y)
//   y == 10: x<512 -> convT W1 tile; x in [512,640) -> convT W2 tile;
//            x==640 -> zero BN stat accumulators; else idle.
// Gene: coalesced float4 x-read into LDS, 25-elem dot, bf16 out (KP-padded).
// convT: [K][N] fp32 -> [N][Kpad] bf16 via 64x64 LDS tile (pad 72).
// ---------------------------------------------------------------------------
__global__ __launch_bounds__(256) void prep_kernel(
    const float* __restrict__ x, const float* __restrict__ gw,
    const float* __restrict__ gb, unsigned short* __restrict__ g_bf,
    const float* __restrict__ W1, unsigned short* __restrict__ W1bT,
    const float* __restrict__ W2, unsigned short* __restrict__ W2bT,
    float* __restrict__ stats) {
  __shared__ char smem[GPB * NGS * 4];   // 20 KB, unioned between paths
  int t = threadIdx.x;

  if (blockIdx.y < 10) {                 // ---- gene path
    float* xs = (float*)smem;
    int b = blockIdx.x;
    int blk = blockIdx.y;
    const float4* src = (const float4*)(x + (size_t)b * (NG * NGS) + blk * (GPB * NGS));
    float4* dst = (float4*)xs;
    for (int i = t; i < (GPB * NGS) / 4; i += 256) dst[i] = src[i];
    __syncthreads();
    if (t < GPB) {
      int gi = blk * GPB + t;
      const float* wp = gw + gi * NGS;
      const float* xp = xs + t * NGS;
      float acc = 0.f;
#pragma unroll
      for (int k = 0; k < NGS; ++k) acc = fmaf(xp[k], wp[k], acc);
      acc += gb[gi];
      g_bf[(size_t)b * KP + gi] = f2bf(fmaxf(acc, 0.f));
    } else if (blk == 9 && t < GPB + (KP - NG)) {
      g_bf[(size_t)b * KP + NG + (t - GPB)] = 0;   // zero-pad k 2000..2047
    }
    return;
  }

  // ---- prep path (y == 10)
  int bx = blockIdx.x;
  if (bx == 640) {                       // zero BN stats (3072 floats)
    for (int i = t; i < 3072; i += 256) stats[i] = 0.f;
    return;
  }
  const float* src; unsigned short* dst; int K, N, Kpad, k0, n0;
  if (bx < 512)      { src = W1; dst = W1bT; K = NG;  N = NH1; Kpad = KP;
                       k0 = (bx & 31) * 64; n0 = (bx >> 5) * 64; }
  else if (bx < 640) { int xi = bx - 512;
                       src = W2; dst = W2bT; K = NH1; N = NH2; Kpad = NH1;
                       k0 = (xi & 15) * 64; n0 = (xi >> 4) * 64; }
  else return;

  unsigned short (*ts)[72] = (unsigned short (*)[72])smem;   // 64x72 = 9.2 KB
  int c4 = (t & 15) * 4;
  int r  = t >> 4;
  for (int rr = r; rr < 64; rr += 16) {
    int k = k0 + rr;
    float4 v = make_float4(0.f, 0.f, 0.f, 0.f);
    if (k < K) v = *(const float4*)&src[(size_t)k * N + n0 + c4];
    ts[rr][c4 + 0] = f2bf(v.x); ts[rr][c4 + 1] = f2bf(v.y);
    ts[rr][c4 + 2] = f2bf(v.z); ts[rr][c4 + 3] = f2bf(v.w);
  }
  __syncthreads();
  int rr8 = (t & 7) * 8;
  int cc  = t >> 3;
  for (int c = cc; c < 64; c += 32) {
    u16x8 val;
#pragma unroll
    for (int i = 0; i < 8; ++i) val[i] = ts[rr8 + i][c];
    *(u16x8*)&dst[(size_t)(n0 + c) * Kpad + k0 + rr8] = val;
  }
}

// ---------------------------------------------------------------------------
// GEMM1: C[M][N] = A(bf16)[M][Kp] * Bt(bf16)[N][Kp]^T, fused BN1 stats.
// 32x64 block tile (grid 512 = 2 blocks/CU -> 2 waves/SIMD), 4 waves each
// 16x64 (1 A-frag x 2 B-frags of 16x16x32). Padded LDS rows (72).
// ---------------------------------------------------------------------------
__global__ __launch_bounds__(256) void gemm1_kernel(
    const unsigned short* __restrict__ A,    // [M][Kp]
    const unsigned short* __restrict__ Bt,   // [N][Kp]
    float* __restrict__ C, float* __restrict__ sum, float* __restrict__ sq,
    int M, int N, int Kp) {
  __shared__ unsigned short As[32][72];
  __shared__ unsigned short Bs[64][72];
  int t = threadIdx.x;
  int m0 = blockIdx.y * 32, n0 = blockIdx.x * 64;
  int wave = t >> 6, lane = t & 63;
  int wm = (wave >> 1) * 16, wn = (wave & 1) * 32;
  int fm = lane & 15, fk = (lane >> 4) * 8;
  int srow = t >> 3, skc = (t & 7) * 8;    // srow 0..31

  f32x4 acc[2];
  acc[0] = (f32x4){0.f, 0.f, 0.f, 0.f};
  acc[1] = (f32x4){0.f, 0.f, 0.f, 0.f};

  const unsigned short* Ap = A + (size_t)(m0 + srow) * Kp + skc;
  const unsigned short* Bp = Bt + (size_t)(n0 + srow) * Kp + skc;
  size_t rstep = 32 * (size_t)Kp;

  u16x8 pa0 = *(const u16x8*)(Ap);
  u16x8 pb0 = *(const u16x8*)(Bp);
  u16x8 pb1 = *(const u16x8*)(Bp + rstep);

  for (int k0 = 0; k0 < Kp; k0 += 64) {
    *(u16x8*)&As[srow][skc]      = pa0;
    *(u16x8*)&Bs[srow][skc]      = pb0;
    *(u16x8*)&Bs[srow + 32][skc] = pb1;
    __syncthreads();
    if (k0 + 64 < Kp) {
      pa0 = *(const u16x8*)(Ap + k0 + 64);
      pb0 = *(const u16x8*)(Bp + k0 + 64);
      pb1 = *(const u16x8*)(Bp + k0 + 64 + rstep);
    }
#pragma unroll
    for (int s = 0; s < 2; ++s) {
      bf16x8 af = *(const bf16x8*)&As[wm + fm][s * 32 + fk];
      bf16x8 b0 = *(const bf16x8*)&Bs[wn + fm][s * 32 + fk];
      bf16x8 b1 = *(const bf16x8*)&Bs[wn + 16 + fm][s * 32 + fk];
      acc[0] = __builtin_amdgcn_mfma_f32_16x16x32_bf16(af, b0, acc[0], 0, 0, 0);
      acc[1] = __builtin_amdgcn_mfma_f32_16x16x32_bf16(af, b1, acc[1], 0, 0, 0);
    }
    __syncthreads();
  }

  int crow = (lane >> 4) * 4, ccol = lane & 15;
#pragma unroll
  for (int j = 0; j < 2; ++j) {
    float s = 0.f, ss = 0.f;
#pragma unroll
    for (int r = 0; r < 4; ++r) {
      float v = acc[j][r];
      int m = m0 + wm + crow + r;
      int n = n0 + wn + j * 16 + ccol;
      C[(size_t)m * N + n] = v;
      s += v;
      ss = fmaf(v, v, ss);
    }
    s  += __shfl_down(s, 32, 64);  s  += __shfl_down(s, 16, 64);
    ss += __shfl_down(ss, 32, 64); ss += __shfl_down(ss, 16, 64);
    if (lane < 16) {
      atomicAdd(&sum[n0 + wn + j * 16 + lane], s);
      atomicAdd(&sq[n0 + wn + j * 16 + lane], ss);
    }
  }
}

// ---------------------------------------------------------------------------
// GEMM2: A = t1 fp32, BN1+ReLU applied during LDS staging (-> bf16);
// B = W2bT bf16. Fused BN2 stats. 32x32 tile (grid 512 = 2 blocks/CU),
// 4 waves each 16x16.
// ---------------------------------------------------------------------------
__global__ __launch_bounds__(256) void gemm2_kernel(
    const float* __restrict__ A,             // [M][Kp] fp32 (t1, pre-BN)
    const unsigned short* __restrict__ Bt,   // [N][Kp] bf16
    float* __restrict__ C, const float* __restrict__ sum1,
    const float* __restrict__ sq1, const float* __restrict__ gam1,
    const float* __restrict__ bet1, float* __restrict__ sum2,
    float* __restrict__ sq2, int M, int N, int Kp) {
  __shared__ unsigned short As[32][72];
  __shared__ unsigned short Bs[32][72];
  int t = threadIdx.x;
  int m0 = blockIdx.y * 32, n0 = blockIdx.x * 32;
  int wave = t >> 6, lane = t & 63;
  int wm = (wave >> 1) * 16, wn = (wave & 1) * 16;
  int fm = lane & 15, fk = (lane >> 4) * 8;
  int srow = t >> 3, skc = (t & 7) * 8;    // srow 0..31

  f32x4 acc = (f32x4){0.f, 0.f, 0.f, 0.f};

  const float* Ap = A + (size_t)(m0 + srow) * Kp + skc;
  const unsigned short* Bp = Bt + (size_t)(n0 + srow) * Kp + skc;

  f32x4 pa0 = *(const f32x4*)(Ap);
  f32x4 pa1 = *(const f32x4*)(Ap + 4);
  u16x8 pb0 = *(const u16x8*)(Bp);

  for (int k0 = 0; k0 < Kp; k0 += 64) {
    // BN1 scale/shift for k = k0+skc+i (same 64 values block-wide -> L1 hot)
    float sc[8], sh[8];
#pragma unroll
    for (int i = 0; i < 8; ++i) {
      int k = k0 + skc + i;
      float mu  = sum1[k] * (1.f / NB);
      float var = sq1[k] * (1.f / NB) - mu * mu;
      float rs  = rsqrtf(var + EPSV);
      sc[i] = gam1[k] * rs;
      sh[i] = fmaf(-mu, sc[i], bet1[k]);
    }
    u16x8 a0;
#pragma unroll
    for (int i = 0; i < 4; ++i) {
      a0[i]     = f2bf(fmaxf(fmaf(pa0[i], sc[i],     sh[i]),     0.f));
      a0[i + 4] = f2bf(fmaxf(fmaf(pa1[i], sc[i + 4], sh[i + 4]), 0.f));
    }
    *(u16x8*)&As[srow][skc] = a0;
    *(u16x8*)&Bs[srow][skc] = pb0;
    __syncthreads();
    if (k0 + 64 < Kp) {
      pa0 = *(const f32x4*)(Ap + k0 + 64);
      pa1 = *(const f32x4*)(Ap + k0 + 64 + 4);
      pb0 = *(const u16x8*)(Bp + k0 + 64);
    }
#pragma unroll
    for (int s = 0; s < 2; ++s) {
      bf16x8 af = *(const bf16x8*)&As[wm + fm][s * 32 + fk];
      bf16x8 bf = *(const bf16x8*)&Bs[wn + fm][s * 32 + fk];
      acc = __builtin_amdgcn_mfma_f32_16x16x32_bf16(af, bf, acc, 0, 0, 0);
    }
    __syncthreads();
  }

  int crow = (lane >> 4) * 4, ccol = lane & 15;
  float s = 0.f, ss = 0.f;
#pragma unroll
  for (int r = 0; r < 4; ++r) {
    float v = acc[r];
    int m = m0 + wm + crow + r;
    int n = n0 + wn + ccol;
    C[(size_t)m * N + n] = v;
    s += v;
    ss = fmaf(v, v, ss);
  }
  s  += __shfl_down(s, 32, 64);  s  += __shfl_down(s, 16, 64);
  ss += __shfl_down(ss, 32, 64); ss += __shfl_down(ss, 16, 64);
  if (lane < 16) {
    atomicAdd(&sum2[n0 + wn + lane], s);
    atomicAdd(&sq2[n0 + wn + lane], ss);
  }
}

// ---------------------------------------------------------------------------
// Final: BN2(inline)+ReLU on t2 row, both heads, softmax. Block per row.
// ---------------------------------------------------------------------------
__global__ __launch_bounds__(256) void final_kernel(
    const float* __restrict__ t2, const float* __restrict__ sum2,
    const float* __restrict__ sq2, const float* __restrict__ gam2,
    const float* __restrict__ bet2, const unsigned short* __restrict__ g_bf,
    const float* __restrict__ Wout, const float* __restrict__ bout,
    const float* __restrict__ Wres, const float* __restrict__ bres,
    float* __restrict__ out) {
  int b = blockIdx.x;
  int t = threadIdx.x;
  float acc[NC] = {};

  if (t < NH2 / 4) {   // main head: BN2 inline
    float4 tv = *(const float4*)&t2[(size_t)b * NH2 + t * 4];
    float raw[4] = {tv.x, tv.y, tv.z, tv.w};
    float hr[4];
#pragma unroll
    for (int i = 0; i < 4; ++i) {
      int c = t * 4 + i;
      float mu  = sum2[c] * (1.f / NB);
      float var = sq2[c] * (1.f / NB) - mu * mu;
      float rs  = rsqrtf(var + EPSV);
      float scv = gam2[c] * rs;
      hr[i] = fmaxf(fmaf(raw[i], scv, fmaf(-mu, scv, bet2[c])), 0.f);
    }
    const float4* wp = (const float4*)&Wout[t * 4 * NC];
    float w[40];
#pragma unroll
    for (int q = 0; q < 10; ++q) {
      float4 wv = wp[q];
      w[q * 4] = wv.x; w[q * 4 + 1] = wv.y; w[q * 4 + 2] = wv.z; w[q * 4 + 3] = wv.w;
    }
#pragma unroll
    for (int r = 0; r < 4; ++r)
#pragma unroll
      for (int c = 0; c < NC; ++c) acc[c] = fmaf(hr[r], w[r * NC + c], acc[c]);
  }

  for (int u = t; u < NG / 4; u += 256) {   // residual head
    u16x4 gv = *(const u16x4*)&g_bf[(size_t)b * KP + u * 4];
    float gr[4] = {bf2f(gv[0]), bf2f(gv[1]), bf2f(gv[2]), bf2f(gv[3])};
    const float4* wp = (const float4*)&Wres[u * 4 * NC];
    float w[40];
#pragma unroll
    for (int q = 0; q < 10; ++q) {
      float4 wv = wp[q];
      w[q * 4] = wv.x; w[q * 4 + 1] = wv.y; w[q * 4 + 2] = wv.z; w[q * 4 + 3] = wv.w;
    }
#pragma unroll
    for (int r = 0; r < 4; ++r)
#pragma unroll
      for (int c = 0; c < NC; ++c) acc[c] = fmaf(gr[r], w[r * NC + c], acc[c]);
  }

  __shared__ float red[4][NC];
  __shared__ float logits[NC];
  int lane = t & 63, wave = t >> 6;
#pragma unroll
  for (int c = 0; c < NC; ++c) {
    float v = acc[c];
    for (int off = 32; off > 0; off >>= 1) v += __shfl_down(v, off, 64);
    if (lane == 0) red[wave][c] = v;
  }
  __syncthreads();
  if (t < NC)
    logits[t] = red[0][t] + red[1][t] + red[2][t] + red[3][t] + bout[t] + bres[t];
  __syncthreads();
  if (t == 0) {
    float mx = logits[0];
#pragma unroll
    for (int c = 1; c < NC; ++c) mx = fmaxf(mx, logits[c]);
    float e[NC], s = 0.f;
#pragma unroll
    for (int c = 0; c < NC; ++c) { e[c] = expf(logits[c] - mx); s += e[c]; }
    float inv = 1.f / s;
#pragma unroll
    for (int c = 0; c < NC; ++c) out[(size_t)b * NC + c] = e[c] * inv;
  }
}

// ---------------------------------------------------------------------------
extern "C" void kernel_launch(void* const* d_in, const int* in_sizes, int n_in,
                              void* d_out, int out_size, void* d_ws, size_t ws_size,
                              hipStream_t stream) {
  const float* x      = (const float*)d_in[0];
  const float* gw     = (const float*)d_in[1];
  const float* gb     = (const float*)d_in[2];
  const float* W1     = (const float*)d_in[3];
  const float* gamma1 = (const float*)d_in[5];
  const float* beta1  = (const float*)d_in[6];
  const float* W2     = (const float*)d_in[7];
  const float* gamma2 = (const float*)d_in[9];
  const float* beta2  = (const float*)d_in[10];
  const float* Wout   = (const float*)d_in[11];
  const float* bout   = (const float*)d_in[12];
  const float* Wres   = (const float*)d_in[13];
  const float* bres   = (const float*)d_in[14];
  float* out = (float*)d_out;

  char* p = (char*)d_ws;
  unsigned short* g_bf = (unsigned short*)p; p += (size_t)NB * KP * 2;    // 4 MB
  unsigned short* W1bT = (unsigned short*)p; p += (size_t)NH1 * KP * 2;   // 4 MB
  unsigned short* W2bT = (unsigned short*)p; p += (size_t)NH2 * NH1 * 2;  // 1 MB
  float* t1 = (float*)p; p += (size_t)NB * NH1 * 4;                       // 4 MB
  float* t2 = (float*)p; p += (size_t)NB * NH2 * 4;                       // 2 MB
  float* stats = (float*)p;
  float* sum1 = stats, *sq1 = stats + 1024, *sum2 = stats + 2048, *sq2 = stats + 2560;

  // gene + weight-transpose + stats-zero in one dispatch
  prep_kernel<<<dim3(NB, 11), 256, 0, stream>>>(x, gw, gb, g_bf,
                                                W1, W1bT, W2, W2bT, stats);

  gemm1_kernel<<<dim3(NH1 / 64, NB / 32), 256, 0, stream>>>(
      g_bf, W1bT, t1, sum1, sq1, NB, NH1, KP);

  gemm2_kernel<<<dim3(NH2 / 32, NB / 32), 256, 0, stream>>>(
      t1, W2bT, t2, sum1, sq1, gamma1, beta1, sum2, sq2, NB, NH2, NH1);

  final_kernel<<<NB, 256, 0, stream>>>(t2, sum2, sq2, gamma2, beta2, g_bf,
                                       Wout, bout, Wres, bres, out);
}